// Round 1
// baseline (448.100 us; speedup 1.0000x reference)
//
#include <hip/hip_runtime.h>
#include <hip/hip_bf16.h>
#include <stdint.h>

#define DMODEL 2048
#define HQ 16
#define HKV 4
#define DH 128
#define SEQT 2048
#define BATCH 2

typedef __bf16 bf16x8 __attribute__((ext_vector_type(8)));
typedef float f32x4 __attribute__((ext_vector_type(4)));
typedef float f32x16 __attribute__((ext_vector_type(16)));
typedef unsigned short u16x4 __attribute__((ext_vector_type(4)));
typedef unsigned short u16x8 __attribute__((ext_vector_type(8)));

__device__ __forceinline__ unsigned short f2bf(float x) {
  __hip_bfloat16 h = __float2bfloat16(x);
  return __builtin_bit_cast(unsigned short, h);
}
__device__ __forceinline__ unsigned int pack2(float a, float b) {
  return (unsigned int)f2bf(a) | ((unsigned int)f2bf(b) << 16);
}

__device__ __forceinline__ void gload_lds16(const void* g, void* lds) {
  __builtin_amdgcn_global_load_lds(
      (const __attribute__((address_space(1))) void*)(uintptr_t)g,
      (__attribute__((address_space(3))) void*)(uint32_t)(uintptr_t)lds,
      16, 0, 0);
}

// ---------------- cast f32 -> bf16 (vectorized, 8 elems/thread) -------------
__global__ __launch_bounds__(256) void cast_bf16_kernel(
    const float* __restrict__ in, unsigned short* __restrict__ out, int n8) {
  int i = blockIdx.x * 256 + threadIdx.x;
  if (i >= n8) return;
  const float4* p = reinterpret_cast<const float4*>(in) + (size_t)i * 2;
  float4 a = p[0], b = p[1];
  u16x8 o;
  o[0] = f2bf(a.x); o[1] = f2bf(a.y); o[2] = f2bf(a.z); o[3] = f2bf(a.w);
  o[4] = f2bf(b.x); o[5] = f2bf(b.y); o[6] = f2bf(b.z); o[7] = f2bf(b.w);
  *(reinterpret_cast<u16x8*>(out) + i) = o;
}

// ---------------- GEMM: C[m,n] = sum_k A[m,k] * B[n,k]  (both row-major) ----
// 128x128 tile, BK=32, 4 waves, 16x16x32 bf16 MFMA, global_load_lds staging.
// z-batched via strides. OUT_BF16 selects bf16 vs f32 C.
template <bool OUT_BF16>
__global__ __launch_bounds__(256) void gemm_bt(
    const unsigned short* __restrict__ A, const unsigned short* __restrict__ B,
    void* __restrict__ Cv, int M, int N, int K,
    long long sA, long long sB, long long sC) {
  A += (size_t)blockIdx.z * sA;
  B += (size_t)blockIdx.z * sB;

  __shared__ alignas(16) unsigned short As[128 * 32];
  __shared__ alignas(16) unsigned short Bs[128 * 32];

  const int tid = threadIdx.x;
  const int wave = tid >> 6, lane = tid & 63;
  const int row0 = blockIdx.x * 128, col0 = blockIdx.y * 128;
  const int wr = (wave >> 1) * 64, wc = (wave & 1) * 64;
  const int l15 = lane & 15, l4 = lane >> 4;
  const int srow = wave * 32 + (lane >> 2);   // staging row (per issue +16)
  const int scol = (lane & 3) * 8;            // staging col (elements)

  f32x4 acc[4][4] = {};

  for (int k0 = 0; k0 < K; k0 += 32) {
    const unsigned short* gA = A + (size_t)(row0 + srow) * K + k0 + scol;
    gload_lds16(gA, (char*)As + wave * 2048);
    gload_lds16(gA + (size_t)16 * K, (char*)As + wave * 2048 + 1024);
    const unsigned short* gB = B + (size_t)(col0 + srow) * K + k0 + scol;
    gload_lds16(gB, (char*)Bs + wave * 2048);
    gload_lds16(gB + (size_t)16 * K, (char*)Bs + wave * 2048 + 1024);
    __syncthreads();  // compiler drains vmcnt before s_barrier

    bf16x8 af[4], bfr[4];
#pragma unroll
    for (int i = 0; i < 4; ++i) {
      af[i]  = *reinterpret_cast<const bf16x8*>(&As[(wr + i * 16 + l15) * 32 + l4 * 8]);
      bfr[i] = *reinterpret_cast<const bf16x8*>(&Bs[(wc + i * 16 + l15) * 32 + l4 * 8]);
    }
#pragma unroll
    for (int i = 0; i < 4; ++i)
#pragma unroll
      for (int j = 0; j < 4; ++j)
        acc[i][j] = __builtin_amdgcn_mfma_f32_16x16x32_bf16(af[i], bfr[j], acc[i][j], 0, 0, 0);
    __syncthreads();
  }

  // epilogue: C/D layout col=lane&15, row=(lane>>4)*4+reg
#pragma unroll
  for (int i = 0; i < 4; ++i) {
    const int rrow = row0 + wr + i * 16 + l4 * 4;
#pragma unroll
    for (int j = 0; j < 4; ++j) {
      const int ccol = col0 + wc + j * 16 + l15;
#pragma unroll
      for (int r = 0; r < 4; ++r) {
        const size_t idx = (size_t)blockIdx.z * sC + (size_t)(rrow + r) * N + ccol;
        if constexpr (OUT_BF16)
          ((unsigned short*)Cv)[idx] = f2bf(acc[i][j][r]);
        else
          ((float*)Cv)[idx] = acc[i][j][r];
      }
    }
  }
}

// ---------------- fused causal GQA flash attention ---------------------------
// Q: [B*T, HQ*128] bf16 ; K: [B*T, HKV*128] bf16 ; VT: [B, HKV*128, T] bf16
// out AO: [B*T, HQ*128] bf16.
// One wave per 32-row q tile; swapped QK^T (S^T = K*Q) via 32x32x16 MFMA;
// in-register online softmax; PV as O^T = V^T * P^T.
__global__ __launch_bounds__(256) void attn_kernel(
    const unsigned short* __restrict__ Q, const unsigned short* __restrict__ Kc,
    const unsigned short* __restrict__ VT, unsigned short* __restrict__ AO) {
  const int wave = threadIdx.x >> 6, lane = threadIdx.x & 63;
  const int h = blockIdx.y, b = blockIdx.z;
  const int hk = h & (HKV - 1);
  const int qbase = blockIdx.x * 128 + wave * 32;
  const int lq = lane & 31, hi = lane >> 5;
  const float scale = 0.08838834764831845f;  // 1/sqrt(128)

  const size_t qrow = (size_t)(b * SEQT + qbase + lq);
  const unsigned short* qp = Q + qrow * (HQ * DH) + h * DH + hi * 8;
  bf16x8 qf[8];
#pragma unroll
  for (int dc = 0; dc < 8; ++dc)
    qf[dc] = *reinterpret_cast<const bf16x8*>(qp + dc * 16);

  f32x16 acc_o[4] = {};
  float mrun = -INFINITY, lrun = 0.f;

  const unsigned short* kb = Kc + (size_t)b * SEQT * (HKV * DH) + hk * DH + hi * 8;
  const unsigned short* vb = VT + ((size_t)b * (HKV * DH) + hk * DH + lq) * SEQT;

  const int nt = qbase / 32 + 1;
  for (int t = 0; t < nt; ++t) {
    const int kvb = t * 32;
    // ---- S^T[kv 32][q 32] = sum_d K[kv,d] * Q[q,d] ----
    f32x16 st = {};
    const unsigned short* kp = kb + (size_t)(kvb + lq) * (HKV * DH);
#pragma unroll
    for (int dc = 0; dc < 8; ++dc) {
      bf16x8 kf = *reinterpret_cast<const bf16x8*>(kp + dc * 16);
      st = __builtin_amdgcn_mfma_f32_32x32x16_bf16(kf, qf[dc], st, 0, 0, 0);
    }
    // ---- scale + causal mask + online softmax (per-lane q column) ----
    float p[16];
    const bool diag = (kvb == qbase);
    float tmax = -INFINITY;
#pragma unroll
    for (int r = 0; r < 16; ++r) {
      const int srw = (r & 3) + 8 * (r >> 2) + 4 * hi;  // kv offset in tile
      float v = st[r] * scale;
      if (diag && srw > lq) v = -INFINITY;
      p[r] = v;
      tmax = fmaxf(tmax, v);
    }
    tmax = fmaxf(tmax, __shfl_xor(tmax, 32));
    const float mnew = fmaxf(mrun, tmax);
    const float fsc = __expf(mrun - mnew);
    float psum = 0.f;
#pragma unroll
    for (int r = 0; r < 16; ++r) { p[r] = __expf(p[r] - mnew); psum += p[r]; }
    psum += __shfl_xor(psum, 32);
    lrun = lrun * fsc + psum;
    mrun = mnew;
#pragma unroll
    for (int dt = 0; dt < 4; ++dt)
#pragma unroll
      for (int r = 0; r < 16; ++r) acc_o[dt][r] *= fsc;

    // ---- P^T -> bf16 B-operand fragments (pack + half-swap via shfl) ----
    unsigned int x0 = pack2(p[0], p[1]),  x1 = pack2(p[2], p[3]);
    unsigned int x2 = pack2(p[4], p[5]),  x3 = pack2(p[6], p[7]);
    unsigned int x4 = pack2(p[8], p[9]),  x5 = pack2(p[10], p[11]);
    unsigned int x6 = pack2(p[12], p[13]), x7 = pack2(p[14], p[15]);
    unsigned int x0s = __shfl_xor(x0, 32), x1s = __shfl_xor(x1, 32);
    unsigned int x2s = __shfl_xor(x2, 32), x3s = __shfl_xor(x3, 32);
    unsigned int x4s = __shfl_xor(x4, 32), x5s = __shfl_xor(x5, 32);
    unsigned int x6s = __shfl_xor(x6, 32), x7s = __shfl_xor(x7, 32);
    union { unsigned int u[4]; bf16x8 v; } pf0, pf1;
    pf0.u[0] = hi ? x2s : x0;  pf0.u[1] = hi ? x3s : x1;
    pf0.u[2] = hi ? x2  : x0s; pf0.u[3] = hi ? x3  : x1s;
    pf1.u[0] = hi ? x6s : x4;  pf1.u[1] = hi ? x7s : x5;
    pf1.u[2] = hi ? x6  : x4s; pf1.u[3] = hi ? x7  : x5s;

    // ---- O^T[d][q] += V^T[d][s] * P^T[s][q] ----
#pragma unroll
    for (int dt = 0; dt < 4; ++dt) {
      const unsigned short* vp = vb + (size_t)dt * 32 * SEQT + kvb + hi * 8;
      bf16x8 v0 = *reinterpret_cast<const bf16x8*>(vp);
      bf16x8 v1 = *reinterpret_cast<const bf16x8*>(vp + 16);
      acc_o[dt] = __builtin_amdgcn_mfma_f32_32x32x16_bf16(v0, pf0.v, acc_o[dt], 0, 0, 0);
      acc_o[dt] = __builtin_amdgcn_mfma_f32_32x32x16_bf16(v1, pf1.v, acc_o[dt], 0, 0, 0);
    }
  }

  const float inv = 1.f / lrun;
  unsigned short* op = AO + qrow * (HQ * DH) + h * DH;
#pragma unroll
  for (int dt = 0; dt < 4; ++dt) {
#pragma unroll
    for (int g2 = 0; g2 < 4; ++g2) {
      u16x4 w;
#pragma unroll
      for (int j = 0; j < 4; ++j) w[j] = f2bf(acc_o[dt][g2 * 4 + j] * inv);
      *reinterpret_cast<u16x4*>(op + dt * 32 + g2 * 8 + 4 * hi) = w;
    }
  }
}

// ---------------- launch ----------------------------------------------------
extern "C" void kernel_launch(void* const* d_in, const int* in_sizes, int n_in,
                              void* d_out, int out_size, void* d_ws, size_t ws_size,
                              hipStream_t stream) {
  const float* x  = (const float*)d_in[0];
  const float* wq = (const float*)d_in[1];
  const float* wk = (const float*)d_in[2];
  const float* wv = (const float*)d_in[3];
  const float* wo = (const float*)d_in[4];
  float* out = (float*)d_out;

  const size_t N_X  = (size_t)BATCH * SEQT * DMODEL;   // 8388608
  const size_t N_WQ = (size_t)HQ * DH * DMODEL;        // 4194304
  const size_t N_WK = (size_t)HKV * DH * DMODEL;       // 1048576
  const size_t N_Q  = (size_t)BATCH * SEQT * HQ * DH;  // 8388608
  const size_t N_K  = (size_t)BATCH * SEQT * HKV * DH; // 2097152

  unsigned short* xb  = (unsigned short*)d_ws;
  unsigned short* wqb = xb  + N_X;
  unsigned short* wkb = wqb + N_WQ;
  unsigned short* wvb = wkb + N_WK;
  unsigned short* wob = wvb + N_WK;
  unsigned short* Qb  = wob + N_WQ;
  unsigned short* Kb  = Qb  + N_Q;
  unsigned short* VTb = Kb  + N_K;
  unsigned short* AOb = VTb + N_K;

  auto cast = [&](const float* in, unsigned short* o, size_t n) {
    int n8 = (int)(n / 8);
    cast_bf16_kernel<<<dim3((n8 + 255) / 256), dim3(256), 0, stream>>>(in, o, n8);
  };
  cast(x, xb, N_X);
  cast(wq, wqb, N_WQ);
  cast(wk, wkb, N_WK);
  cast(wv, wvb, N_WK);
  cast(wo, wob, N_WQ);

  // Q = x @ wq^T : [4096, 2048]
  gemm_bt<true><<<dim3(32, 16, 1), 256, 0, stream>>>(xb, wqb, Qb, BATCH * SEQT, 2048, DMODEL, 0, 0, 0);
  // K = x @ wk^T : [4096, 512]
  gemm_bt<true><<<dim3(32, 4, 1), 256, 0, stream>>>(xb, wkb, Kb, BATCH * SEQT, 512, DMODEL, 0, 0, 0);
  // V^T[b] = wv @ x_b^T : [512, 2048] per batch
  gemm_bt<true><<<dim3(4, 16, BATCH), 256, 0, stream>>>(
      wvb, xb, VTb, 512, SEQT, DMODEL,
      0, (long long)SEQT * DMODEL, (long long)512 * SEQT);
  // attention
  attn_kernel<<<dim3(SEQT / 128, HQ, BATCH), 256, 0, stream>>>(Qb, Kb, VTb, AOb);
  // out = AO @ wo^T : [4096, 2048] f32
  gemm_bt<false><<<dim3(32, 16, 1), 256, 0, stream>>>(AOb, wob, out, BATCH * SEQT, 2048, DMODEL, 0, 0, 0);
}

// Round 2
// 338.510 us; speedup vs baseline: 1.3237x; 1.3237x over previous
//
#include <hip/hip_runtime.h>
#include <hip/hip_bf16.h>
#include <stdint.h>

#define DMODEL 2048
#define HQ 16
#define HKV 4
#define DH 128
#define SEQT 2048
#define BATCH 2

typedef __bf16 bf16x8 __attribute__((ext_vector_type(8)));
typedef float f32x4 __attribute__((ext_vector_type(4)));
typedef float f32x16 __attribute__((ext_vector_type(16)));
typedef unsigned short u16x4 __attribute__((ext_vector_type(4)));
typedef unsigned short u16x8 __attribute__((ext_vector_type(8)));

__device__ __forceinline__ unsigned short f2bf(float x) {
  __hip_bfloat16 h = __float2bfloat16(x);
  return __builtin_bit_cast(unsigned short, h);
}
__device__ __forceinline__ unsigned int pack2(float a, float b) {
  return (unsigned int)f2bf(a) | ((unsigned int)f2bf(b) << 16);
}

__device__ __forceinline__ void gload_lds16(const void* g, void* lds) {
  __builtin_amdgcn_global_load_lds(
      (const __attribute__((address_space(1))) void*)(uintptr_t)g,
      (__attribute__((address_space(3))) void*)(uint32_t)(uintptr_t)lds,
      16, 0, 0);
}

// ---------------- cast f32 -> bf16 (vectorized, 8 elems/thread) -------------
__global__ __launch_bounds__(256) void cast_bf16_kernel(
    const float* __restrict__ in, unsigned short* __restrict__ out, int n8) {
  int i = blockIdx.x * 256 + threadIdx.x;
  if (i >= n8) return;
  const float4* p = reinterpret_cast<const float4*>(in) + (size_t)i * 2;
  float4 a = p[0], b = p[1];
  u16x8 o;
  o[0] = f2bf(a.x); o[1] = f2bf(a.y); o[2] = f2bf(a.z); o[3] = f2bf(a.w);
  o[4] = f2bf(b.x); o[5] = f2bf(b.y); o[6] = f2bf(b.z); o[7] = f2bf(b.w);
  *(reinterpret_cast<u16x8*>(out) + i) = o;
}

// ---------------- GEMM: C[m,n] = sum_k A[m,k] * B[n,k]  (both row-major) ----
template <bool OUT_BF16>
__global__ __launch_bounds__(256) void gemm_bt(
    const unsigned short* __restrict__ A, const unsigned short* __restrict__ B,
    void* __restrict__ Cv, int M, int N, int K,
    long long sA, long long sB, long long sC) {
  A += (size_t)blockIdx.z * sA;
  B += (size_t)blockIdx.z * sB;

  __shared__ alignas(16) unsigned short As[128 * 32];
  __shared__ alignas(16) unsigned short Bs[128 * 32];

  const int tid = threadIdx.x;
  const int wave = tid >> 6, lane = tid & 63;
  const int row0 = blockIdx.x * 128, col0 = blockIdx.y * 128;
  const int wr = (wave >> 1) * 64, wc = (wave & 1) * 64;
  const int l15 = lane & 15, l4 = lane >> 4;
  const int srow = wave * 32 + (lane >> 2);
  const int scol = (lane & 3) * 8;

  f32x4 acc[4][4] = {};

  for (int k0 = 0; k0 < K; k0 += 32) {
    const unsigned short* gA = A + (size_t)(row0 + srow) * K + k0 + scol;
    gload_lds16(gA, (char*)As + wave * 2048);
    gload_lds16(gA + (size_t)16 * K, (char*)As + wave * 2048 + 1024);
    const unsigned short* gB = B + (size_t)(col0 + srow) * K + k0 + scol;
    gload_lds16(gB, (char*)Bs + wave * 2048);
    gload_lds16(gB + (size_t)16 * K, (char*)Bs + wave * 2048 + 1024);
    __syncthreads();

    bf16x8 af[4], bfr[4];
#pragma unroll
    for (int i = 0; i < 4; ++i) {
      af[i]  = *reinterpret_cast<const bf16x8*>(&As[(wr + i * 16 + l15) * 32 + l4 * 8]);
      bfr[i] = *reinterpret_cast<const bf16x8*>(&Bs[(wc + i * 16 + l15) * 32 + l4 * 8]);
    }
#pragma unroll
    for (int i = 0; i < 4; ++i)
#pragma unroll
      for (int j = 0; j < 4; ++j)
        acc[i][j] = __builtin_amdgcn_mfma_f32_16x16x32_bf16(af[i], bfr[j], acc[i][j], 0, 0, 0);
    __syncthreads();
  }

#pragma unroll
  for (int i = 0; i < 4; ++i) {
    const int rrow = row0 + wr + i * 16 + l4 * 4;
#pragma unroll
    for (int j = 0; j < 4; ++j) {
      const int ccol = col0 + wc + j * 16 + l15;
#pragma unroll
      for (int r = 0; r < 4; ++r) {
        const size_t idx = (size_t)blockIdx.z * sC + (size_t)(rrow + r) * N + ccol;
        if constexpr (OUT_BF16)
          ((unsigned short*)Cv)[idx] = f2bf(acc[i][j][r]);
        else
          ((float*)Cv)[idx] = acc[i][j][r];
      }
    }
  }
}

// ---------------- fused causal GQA flash attention ---------------------------
// Block = (b, hk, q-tile j); 4 waves = the 4 q-heads sharing kv head hk.
// K,V tiles staged in LDS once per block (fragment-major, conflict-free),
// identical causal range for all waves (no divergence). 1-D grid with (b,hk)
// in low 3 bits (XCD pinning) and complementary-j pairing for load balance.
__global__ __launch_bounds__(256) void attn_kernel(
    const unsigned short* __restrict__ Q, const unsigned short* __restrict__ Kc,
    const unsigned short* __restrict__ VT, unsigned short* __restrict__ AO) {
  __shared__ alignas(16) unsigned short Ks[8 * 512];   // 8 frags x 1KB
  __shared__ alignas(16) unsigned short Vs[8 * 512];   // 8 frags x 1KB

  const int tid = threadIdx.x;
  const int wave = tid >> 6, lane = tid & 63;
  const int bid = blockIdx.x;
  const int round = bid >> 8, pairslot = bid & 255;
  const int bhk = pairslot & 7;
  const int jp = pairslot >> 3;              // 0..31
  const int j = round ? jp : 63 - jp;        // q-tile index 0..63
  const int b = bhk >> 2, hk = bhk & 3;
  const int h = hk + wave * 4;               // head = g*H_K + hk
  const int q0 = j * 32;
  const int lq = lane & 31, hi = lane >> 5, l5 = hi;
  const float SCL2E = 0.1275174473f;         // 1/sqrt(128) * log2(e)

  const size_t qrow = (size_t)(b * SEQT + q0 + lq);
  const unsigned short* qp = Q + qrow * (HQ * DH) + h * DH + hi * 8;
  bf16x8 qf[8];
#pragma unroll
  for (int dc = 0; dc < 8; ++dc)
    qf[dc] = *reinterpret_cast<const bf16x8*>(qp + dc * 16);

  f32x16 acc_o[4] = {};
  float mrun = -INFINITY, lrun = 0.f;

  const unsigned short* kbase = Kc + (size_t)b * SEQT * (HKV * DH) + hk * DH;
  const unsigned short* vtb = VT + ((size_t)b * (HKV * DH) + hk * DH) * SEQT;

  for (int t = 0; t <= j; ++t) {
    const int kvb = t * 32;
    // ---- stage K,V tiles (frag-major: frag f at f*1024 bytes, lane*16) ----
#pragma unroll
    for (int issue = 0; issue < 2; ++issue) {
      const int dc = issue * 4 + wave;
      const unsigned short* g = kbase + (size_t)(kvb + lq) * (HKV * DH) + dc * 16 + l5 * 8;
      gload_lds16(g, (char*)Ks + (issue * 256 + wave * 64) * 16);
    }
#pragma unroll
    for (int issue = 0; issue < 2; ++issue) {
      const int f = issue * 4 + wave, dt = f >> 1, ks = f & 1;
      const unsigned short* g = vtb + (size_t)(dt * 32 + lq) * SEQT + kvb + ks * 16 + l5 * 8;
      gload_lds16(g, (char*)Vs + (issue * 256 + wave * 64) * 16);
    }
    __syncthreads();

    // ---- S^T[kv][q] = sum_d K[kv,d] * Q[q,d] ----
    f32x16 st = {};
#pragma unroll
    for (int dc = 0; dc < 8; ++dc) {
      bf16x8 kf = *reinterpret_cast<const bf16x8*>((char*)Ks + dc * 1024 + lane * 16);
      st = __builtin_amdgcn_mfma_f32_32x32x16_bf16(kf, qf[dc], st, 0, 0, 0);
    }

    // ---- scaled (log2-domain) + causal mask + online softmax ----
    float p[16];
    const bool diag = (t == j);
    float tmax = -INFINITY;
#pragma unroll
    for (int r = 0; r < 16; ++r) {
      const int srw = (r & 3) + 8 * (r >> 2) + 4 * hi;
      float v = st[r] * SCL2E;
      if (diag && srw > lq) v = -INFINITY;
      p[r] = v;
      tmax = fmaxf(tmax, v);
    }
    tmax = fmaxf(tmax, __shfl_xor(tmax, 32));
    if (!__all(tmax <= mrun)) {
      const float mnew = fmaxf(mrun, tmax);
      const float fsc = __builtin_amdgcn_exp2f(mrun - mnew);
      lrun *= fsc;
#pragma unroll
      for (int dt = 0; dt < 4; ++dt)
#pragma unroll
        for (int r = 0; r < 16; ++r) acc_o[dt][r] *= fsc;
      mrun = mnew;
    }
    float psum = 0.f;
#pragma unroll
    for (int r = 0; r < 16; ++r) {
      p[r] = __builtin_amdgcn_exp2f(p[r] - mrun);
      psum += p[r];
    }
    psum += __shfl_xor(psum, 32);
    lrun += psum;

    // ---- P^T -> bf16 B-operand fragments (pack + half-swap via shfl) ----
    unsigned int x0 = pack2(p[0], p[1]),  x1 = pack2(p[2], p[3]);
    unsigned int x2 = pack2(p[4], p[5]),  x3 = pack2(p[6], p[7]);
    unsigned int x4 = pack2(p[8], p[9]),  x5 = pack2(p[10], p[11]);
    unsigned int x6 = pack2(p[12], p[13]), x7 = pack2(p[14], p[15]);
    unsigned int x0s = __shfl_xor(x0, 32), x1s = __shfl_xor(x1, 32);
    unsigned int x2s = __shfl_xor(x2, 32), x3s = __shfl_xor(x3, 32);
    unsigned int x4s = __shfl_xor(x4, 32), x5s = __shfl_xor(x5, 32);
    unsigned int x6s = __shfl_xor(x6, 32), x7s = __shfl_xor(x7, 32);
    union { unsigned int u[4]; bf16x8 v; } pf0, pf1;
    pf0.u[0] = hi ? x2s : x0;  pf0.u[1] = hi ? x3s : x1;
    pf0.u[2] = hi ? x2  : x0s; pf0.u[3] = hi ? x3  : x1s;
    pf1.u[0] = hi ? x6s : x4;  pf1.u[1] = hi ? x7s : x5;
    pf1.u[2] = hi ? x6  : x4s; pf1.u[3] = hi ? x7  : x5s;

    // ---- O^T[d][q] += V^T[d][s] * P^T[s][q] ----
#pragma unroll
    for (int dt = 0; dt < 4; ++dt) {
      bf16x8 v0 = *reinterpret_cast<const bf16x8*>((char*)Vs + (dt * 2 + 0) * 1024 + lane * 16);
      bf16x8 v1 = *reinterpret_cast<const bf16x8*>((char*)Vs + (dt * 2 + 1) * 1024 + lane * 16);
      acc_o[dt] = __builtin_amdgcn_mfma_f32_32x32x16_bf16(v0, pf0.v, acc_o[dt], 0, 0, 0);
      acc_o[dt] = __builtin_amdgcn_mfma_f32_32x32x16_bf16(v1, pf1.v, acc_o[dt], 0, 0, 0);
    }
    __syncthreads();
  }

  const float inv = 1.f / lrun;
  unsigned short* op = AO + qrow * (HQ * DH) + h * DH;
#pragma unroll
  for (int dt = 0; dt < 4; ++dt) {
#pragma unroll
    for (int g2 = 0; g2 < 4; ++g2) {
      u16x4 w;
#pragma unroll
      for (int jj = 0; jj < 4; ++jj) w[jj] = f2bf(acc_o[dt][g2 * 4 + jj] * inv);
      *reinterpret_cast<u16x4*>(op + dt * 32 + g2 * 8 + 4 * hi) = w;
    }
  }
}

// ---------------- launch ----------------------------------------------------
extern "C" void kernel_launch(void* const* d_in, const int* in_sizes, int n_in,
                              void* d_out, int out_size, void* d_ws, size_t ws_size,
                              hipStream_t stream) {
  const float* x  = (const float*)d_in[0];
  const float* wq = (const float*)d_in[1];
  const float* wk = (const float*)d_in[2];
  const float* wv = (const float*)d_in[3];
  const float* wo = (const float*)d_in[4];
  float* out = (float*)d_out;

  const size_t N_X  = (size_t)BATCH * SEQT * DMODEL;
  const size_t N_WQ = (size_t)HQ * DH * DMODEL;
  const size_t N_WK = (size_t)HKV * DH * DMODEL;
  const size_t N_Q  = (size_t)BATCH * SEQT * HQ * DH;
  const size_t N_K  = (size_t)BATCH * SEQT * HKV * DH;

  unsigned short* xb  = (unsigned short*)d_ws;
  unsigned short* wqb = xb  + N_X;
  unsigned short* wkb = wqb + N_WQ;
  unsigned short* wvb = wkb + N_WK;
  unsigned short* wob = wvb + N_WK;
  unsigned short* Qb  = wob + N_WQ;
  unsigned short* Kb  = Qb  + N_Q;
  unsigned short* VTb = Kb  + N_K;
  unsigned short* AOb = VTb + N_K;

  auto cast = [&](const float* in, unsigned short* o, size_t n) {
    int n8 = (int)(n / 8);
    cast_bf16_kernel<<<dim3((n8 + 255) / 256), dim3(256), 0, stream>>>(in, o, n8);
  };
  cast(x, xb, N_X);
  cast(wq, wqb, N_WQ);
  cast(wk, wkb, N_WK);
  cast(wv, wvb, N_WK);
  cast(wo, wob, N_WQ);

  gemm_bt<true><<<dim3(32, 16, 1), 256, 0, stream>>>(xb, wqb, Qb, BATCH * SEQT, 2048, DMODEL, 0, 0, 0);
  gemm_bt<true><<<dim3(32, 4, 1), 256, 0, stream>>>(xb, wkb, Kb, BATCH * SEQT, 512, DMODEL, 0, 0, 0);
  gemm_bt<true><<<dim3(4, 16, BATCH), 256, 0, stream>>>(
      wvb, xb, VTb, 512, SEQT, DMODEL,
      0, (long long)SEQT * DMODEL, (long long)512 * SEQT);
  attn_kernel<<<dim3(512, 1, 1), 256, 0, stream>>>(Qb, Kb, VTb, AOb);
  gemm_bt<false><<<dim3(32, 16, 1), 256, 0, stream>>>(AOb, wob, out, BATCH * SEQT, 2048, DMODEL, 0, 0, 0);
}

// Round 3
// 214.674 us; speedup vs baseline: 2.0874x; 1.5769x over previous
//
#include <hip/hip_runtime.h>
#include <hip/hip_bf16.h>
#include <stdint.h>

#define DMODEL 2048
#define HQ 16
#define HKV 4
#define DH 128
#define SEQT 2048
#define BATCH 2

typedef __bf16 bf16x8 __attribute__((ext_vector_type(8)));
typedef float f32x4 __attribute__((ext_vector_type(4)));
typedef float f32x16 __attribute__((ext_vector_type(16)));
typedef unsigned short u16x4 __attribute__((ext_vector_type(4)));
typedef unsigned short u16x8 __attribute__((ext_vector_type(8)));

__device__ __forceinline__ unsigned short f2bf(float x) {
  __hip_bfloat16 h = __float2bfloat16(x);
  return __builtin_bit_cast(unsigned short, h);
}
__device__ __forceinline__ unsigned int pack2(float a, float b) {
  return (unsigned int)f2bf(a) | ((unsigned int)f2bf(b) << 16);
}

__device__ __forceinline__ void gload_lds16(const void* g, void* lds) {
  __builtin_amdgcn_global_load_lds(
      (const __attribute__((address_space(1))) void*)(uintptr_t)g,
      (__attribute__((address_space(3))) void*)(uint32_t)(uintptr_t)lds,
      16, 0, 0);
}

// ---------------- fused cast f32 -> bf16 (all 5 tensors, one launch) --------
__global__ __launch_bounds__(256) void cast_all_kernel(
    const float* __restrict__ x, const float* __restrict__ wq,
    const float* __restrict__ wk, const float* __restrict__ wv,
    const float* __restrict__ wo,
    unsigned short* __restrict__ xb, unsigned short* __restrict__ wqb,
    unsigned short* __restrict__ wkb, unsigned short* __restrict__ wvb,
    unsigned short* __restrict__ wob) {
  int i = blockIdx.x * 256 + threadIdx.x;
  const float* in; unsigned short* out; int off;
  if (i < 1048576)      { in = x;  out = xb;  off = i; }
  else if (i < 1572864) { in = wq; out = wqb; off = i - 1048576; }
  else if (i < 1703936) { in = wk; out = wkb; off = i - 1572864; }
  else if (i < 1835008) { in = wv; out = wvb; off = i - 1703936; }
  else                  { in = wo; out = wob; off = i - 1835008; }
  const float4* p = reinterpret_cast<const float4*>(in) + (size_t)off * 2;
  float4 a = p[0], b = p[1];
  u16x8 o;
  o[0] = f2bf(a.x); o[1] = f2bf(a.y); o[2] = f2bf(a.z); o[3] = f2bf(a.w);
  o[4] = f2bf(b.x); o[5] = f2bf(b.y); o[6] = f2bf(b.z); o[7] = f2bf(b.w);
  *(reinterpret_cast<u16x8*>(out) + off) = o;
}

// ---------------- GEMM body: C[m,n]=sum_k A[m,k]*B[n,k], BK=64 (2x32 halves)
template <bool OUT_BF16>
__device__ __forceinline__ void gemm_body(
    unsigned short* As, unsigned short* Bs,  // [2][128*32] each
    const unsigned short* __restrict__ A, const unsigned short* __restrict__ B,
    void* __restrict__ Cv, int N, int K, int row0, int col0) {
  const int tid = threadIdx.x;
  const int wave = tid >> 6, lane = tid & 63;
  const int wr = (wave >> 1) * 64, wc = (wave & 1) * 64;
  const int l15 = lane & 15, l4 = lane >> 4;
  const int srow = wave * 32 + (lane >> 2);
  const int scol = (lane & 3) * 8;

  f32x4 acc[4][4] = {};

  for (int k0 = 0; k0 < K; k0 += 64) {
#pragma unroll
    for (int h = 0; h < 2; ++h) {
      const unsigned short* gA = A + (size_t)(row0 + srow) * K + k0 + h * 32 + scol;
      gload_lds16(gA, (char*)As + h * 8192 + wave * 2048);
      gload_lds16(gA + (size_t)16 * K, (char*)As + h * 8192 + wave * 2048 + 1024);
      const unsigned short* gB = B + (size_t)(col0 + srow) * K + k0 + h * 32 + scol;
      gload_lds16(gB, (char*)Bs + h * 8192 + wave * 2048);
      gload_lds16(gB + (size_t)16 * K, (char*)Bs + h * 8192 + wave * 2048 + 1024);
    }
    __syncthreads();

    bf16x8 af[2][4], bfr[2][4];
#pragma unroll
    for (int h = 0; h < 2; ++h)
#pragma unroll
      for (int i = 0; i < 4; ++i) {
        af[h][i]  = *reinterpret_cast<const bf16x8*>(&As[h * 4096 + (wr + i * 16 + l15) * 32 + l4 * 8]);
        bfr[h][i] = *reinterpret_cast<const bf16x8*>(&Bs[h * 4096 + (wc + i * 16 + l15) * 32 + l4 * 8]);
      }
#pragma unroll
    for (int h = 0; h < 2; ++h)
#pragma unroll
      for (int i = 0; i < 4; ++i)
#pragma unroll
        for (int j = 0; j < 4; ++j)
          acc[i][j] = __builtin_amdgcn_mfma_f32_16x16x32_bf16(af[h][i], bfr[h][j], acc[i][j], 0, 0, 0);
    __syncthreads();
  }

#pragma unroll
  for (int i = 0; i < 4; ++i) {
    const int rrow = row0 + wr + i * 16 + l4 * 4;
#pragma unroll
    for (int j = 0; j < 4; ++j) {
      const int ccol = col0 + wc + j * 16 + l15;
#pragma unroll
      for (int r = 0; r < 4; ++r) {
        const size_t idx = (size_t)(rrow + r) * N + ccol;
        if constexpr (OUT_BF16)
          ((unsigned short*)Cv)[idx] = f2bf(acc[i][j][r]);
        else
          ((float*)Cv)[idx] = acc[i][j][r];
      }
    }
  }
}

template <bool OUT_BF16>
__global__ __launch_bounds__(256) void gemm_bt(
    const unsigned short* __restrict__ A, const unsigned short* __restrict__ B,
    void* __restrict__ Cv, int N, int K) {
  __shared__ alignas(16) unsigned short As[2][128 * 32];
  __shared__ alignas(16) unsigned short Bs[2][128 * 32];
  gemm_body<OUT_BF16>(&As[0][0], &Bs[0][0], A, B, Cv, N, K,
                      blockIdx.x * 128, blockIdx.y * 128);
}

// K-proj (blocks 0..127: 32x4 tiles) + V^T-proj (blocks 128..255: 4x16x2)
__global__ __launch_bounds__(256) void gemm_kv(
    const unsigned short* __restrict__ xb, const unsigned short* __restrict__ wkb,
    const unsigned short* __restrict__ wvb,
    unsigned short* __restrict__ Kb, unsigned short* __restrict__ VTb) {
  __shared__ alignas(16) unsigned short As[2][128 * 32];
  __shared__ alignas(16) unsigned short Bs[2][128 * 32];
  const int bid = blockIdx.x;
  if (bid < 128) {
    const int tx = bid >> 2, ty = bid & 3;
    gemm_body<true>(&As[0][0], &Bs[0][0], xb, wkb, Kb, 512, DMODEL,
                    tx * 128, ty * 128);
  } else {
    const int lb = bid - 128;
    const int tz = lb & 1, ty = (lb >> 1) & 15, tx = lb >> 5;
    gemm_body<true>(&As[0][0], &Bs[0][0], wvb,
                    xb + (size_t)tz * SEQT * DMODEL,
                    VTb + (size_t)tz * 512 * SEQT, SEQT, DMODEL,
                    tx * 128, ty * 128);
  }
}

// ---------------- fused causal GQA flash attention ---------------------------
// Block = (b, hk, q-tile j of 32 rows); 4 waves = 4 q-heads sharing kv head.
// KVBLK=64, double-buffered LDS with prefetch (stage t+1 before compute t,
// one barrier per iteration). Swapped QK^T, in-register online softmax.
__global__ __launch_bounds__(256, 2) void attn_kernel(
    const unsigned short* __restrict__ Q, const unsigned short* __restrict__ Kc,
    const unsigned short* __restrict__ VT, unsigned short* __restrict__ AO) {
  __shared__ alignas(16) unsigned short Ks[2][16 * 512];   // 16KB per buf
  __shared__ alignas(16) unsigned short Vs[2][16 * 512];

  const int tid = threadIdx.x;
  const int wave = tid >> 6, lane = tid & 63;
  const int bid = blockIdx.x;
  const int round = bid >> 8, pairslot = bid & 255;
  const int bhk = pairslot & 7;
  const int jp = pairslot >> 3;
  const int j = round ? jp : 63 - jp;        // q-tile index 0..63
  const int b = bhk >> 2, hk = bhk & 3;
  const int h = hk + wave * 4;
  const int q0 = j * 32;
  const int jt = j >> 1;                     // last 64-wide kv tile index
  const int lq = lane & 31, hi = lane >> 5;
  const float SCL2E = 0.1275174473f;         // 1/sqrt(128) * log2(e)

  const size_t qrow = (size_t)(b * SEQT + q0 + lq);
  const unsigned short* qp = Q + qrow * (HQ * DH) + h * DH + hi * 8;
  bf16x8 qf[8];
#pragma unroll
  for (int dc = 0; dc < 8; ++dc)
    qf[dc] = *reinterpret_cast<const bf16x8*>(qp + dc * 16);

  f32x16 acc_o[4] = {};
  float mrun = -INFINITY, lrun = 0.f;

  const unsigned short* kbase = Kc + (size_t)b * SEQT * (HKV * DH) + hk * DH;
  const unsigned short* vtb = VT + ((size_t)b * (HKV * DH) + hk * DH) * SEQT;

  auto STAGE = [&](int buf, int kvb2) {
#pragma unroll
    for (int i = 0; i < 4; ++i) {
      const int f = i * 4 + wave;            // K frag: sub=f>>3, dc=f&7
      const int sub = f >> 3, dc = f & 7;
      const unsigned short* g = kbase + (size_t)(kvb2 + sub * 32 + lq) * (HKV * DH) + dc * 16 + hi * 8;
      gload_lds16(g, (char*)Ks[buf] + f * 1024);
    }
#pragma unroll
    for (int i = 0; i < 4; ++i) {
      const int f = i * 4 + wave;            // V frag: dt=f>>2, ks=f&3
      const int dt = f >> 2, ks = f & 3;
      const unsigned short* g = vtb + (size_t)(dt * 32 + lq) * SEQT + kvb2 + ks * 16 + hi * 8;
      gload_lds16(g, (char*)Vs[buf] + f * 1024);
    }
  };

  STAGE(0, 0);
  __syncthreads();
  int cur = 0;

  for (int t = 0; t <= jt; ++t) {
    if (t < jt) STAGE(cur ^ 1, (t + 1) * 64);
    const int kvb = t * 64;
    const bool s1v = (kvb + 32 <= q0);       // second 32-kv subtile active
    const bool d0 = (kvb == q0), d1 = (kvb + 32 == q0);

    // ---- S^T = K * Q (two independent 32x32 chains) ----
    f32x16 st0 = {}, st1 = {};
    __builtin_amdgcn_s_setprio(1);
#pragma unroll
    for (int dc = 0; dc < 8; ++dc) {
      bf16x8 kf = *reinterpret_cast<const bf16x8*>((char*)Ks[cur] + dc * 1024 + lane * 16);
      st0 = __builtin_amdgcn_mfma_f32_32x32x16_bf16(kf, qf[dc], st0, 0, 0, 0);
    }
    if (s1v) {
#pragma unroll
      for (int dc = 0; dc < 8; ++dc) {
        bf16x8 kf = *reinterpret_cast<const bf16x8*>((char*)Ks[cur] + (8 + dc) * 1024 + lane * 16);
        st1 = __builtin_amdgcn_mfma_f32_32x32x16_bf16(kf, qf[dc], st1, 0, 0, 0);
      }
    }
    __builtin_amdgcn_s_setprio(0);

    // ---- mask + online softmax over up to 32 p-values ----
    float p0[16], p1[16];
    float tmax = -INFINITY;
#pragma unroll
    for (int r = 0; r < 16; ++r) {
      const int srw = (r & 3) + 8 * (r >> 2) + 4 * hi;
      float v = st0[r] * SCL2E;
      if (d0 && srw > lq) v = -INFINITY;
      p0[r] = v; tmax = fmaxf(tmax, v);
    }
    if (s1v) {
#pragma unroll
      for (int r = 0; r < 16; ++r) {
        const int srw = (r & 3) + 8 * (r >> 2) + 4 * hi;
        float v = st1[r] * SCL2E;
        if (d1 && srw > lq) v = -INFINITY;
        p1[r] = v; tmax = fmaxf(tmax, v);
      }
    }
    tmax = fmaxf(tmax, __shfl_xor(tmax, 32));
    if (!__all(tmax <= mrun)) {
      const float mnew = fmaxf(mrun, tmax);
      const float fsc = __builtin_amdgcn_exp2f(mrun - mnew);
      lrun *= fsc;
#pragma unroll
      for (int dt = 0; dt < 4; ++dt)
#pragma unroll
        for (int r = 0; r < 16; ++r) acc_o[dt][r] *= fsc;
      mrun = mnew;
    }
    float psum = 0.f;
#pragma unroll
    for (int r = 0; r < 16; ++r) { p0[r] = __builtin_amdgcn_exp2f(p0[r] - mrun); psum += p0[r]; }
    if (s1v) {
#pragma unroll
      for (int r = 0; r < 16; ++r) { p1[r] = __builtin_amdgcn_exp2f(p1[r] - mrun); psum += p1[r]; }
    }
    psum += __shfl_xor(psum, 32);
    lrun += psum;

    // ---- pack P^T into B-operand fragments ----
    union { unsigned int u[4]; bf16x8 v; } pf0, pf1, pf2, pf3;
    {
      unsigned int x0 = pack2(p0[0], p0[1]),  x1 = pack2(p0[2], p0[3]);
      unsigned int x2 = pack2(p0[4], p0[5]),  x3 = pack2(p0[6], p0[7]);
      unsigned int x4 = pack2(p0[8], p0[9]),  x5 = pack2(p0[10], p0[11]);
      unsigned int x6 = pack2(p0[12], p0[13]), x7 = pack2(p0[14], p0[15]);
      unsigned int x0s = __shfl_xor(x0, 32), x1s = __shfl_xor(x1, 32);
      unsigned int x2s = __shfl_xor(x2, 32), x3s = __shfl_xor(x3, 32);
      unsigned int x4s = __shfl_xor(x4, 32), x5s = __shfl_xor(x5, 32);
      unsigned int x6s = __shfl_xor(x6, 32), x7s = __shfl_xor(x7, 32);
      pf0.u[0] = hi ? x2s : x0;  pf0.u[1] = hi ? x3s : x1;
      pf0.u[2] = hi ? x2  : x0s; pf0.u[3] = hi ? x3  : x1s;
      pf1.u[0] = hi ? x6s : x4;  pf1.u[1] = hi ? x7s : x5;
      pf1.u[2] = hi ? x6  : x4s; pf1.u[3] = hi ? x7  : x5s;
    }
    if (s1v) {
      unsigned int x0 = pack2(p1[0], p1[1]),  x1 = pack2(p1[2], p1[3]);
      unsigned int x2 = pack2(p1[4], p1[5]),  x3 = pack2(p1[6], p1[7]);
      unsigned int x4 = pack2(p1[8], p1[9]),  x5 = pack2(p1[10], p1[11]);
      unsigned int x6 = pack2(p1[12], p1[13]), x7 = pack2(p1[14], p1[15]);
      unsigned int x0s = __shfl_xor(x0, 32), x1s = __shfl_xor(x1, 32);
      unsigned int x2s = __shfl_xor(x2, 32), x3s = __shfl_xor(x3, 32);
      unsigned int x4s = __shfl_xor(x4, 32), x5s = __shfl_xor(x5, 32);
      unsigned int x6s = __shfl_xor(x6, 32), x7s = __shfl_xor(x7, 32);
      pf2.u[0] = hi ? x2s : x0;  pf2.u[1] = hi ? x3s : x1;
      pf2.u[2] = hi ? x2  : x0s; pf2.u[3] = hi ? x3  : x1s;
      pf3.u[0] = hi ? x6s : x4;  pf3.u[1] = hi ? x7s : x5;
      pf3.u[2] = hi ? x6  : x4s; pf3.u[3] = hi ? x7  : x5s;
    }

    // ---- O^T[d][q] += V^T[d][s] * P^T[s][q] ----
    __builtin_amdgcn_s_setprio(1);
#pragma unroll
    for (int dt = 0; dt < 4; ++dt) {
      bf16x8 v0 = *reinterpret_cast<const bf16x8*>((char*)Vs[cur] + (dt * 4 + 0) * 1024 + lane * 16);
      bf16x8 v1 = *reinterpret_cast<const bf16x8*>((char*)Vs[cur] + (dt * 4 + 1) * 1024 + lane * 16);
      acc_o[dt] = __builtin_amdgcn_mfma_f32_32x32x16_bf16(v0, pf0.v, acc_o[dt], 0, 0, 0);
      acc_o[dt] = __builtin_amdgcn_mfma_f32_32x32x16_bf16(v1, pf1.v, acc_o[dt], 0, 0, 0);
    }
    if (s1v) {
#pragma unroll
      for (int dt = 0; dt < 4; ++dt) {
        bf16x8 v2 = *reinterpret_cast<const bf16x8*>((char*)Vs[cur] + (dt * 4 + 2) * 1024 + lane * 16);
        bf16x8 v3 = *reinterpret_cast<const bf16x8*>((char*)Vs[cur] + (dt * 4 + 3) * 1024 + lane * 16);
        acc_o[dt] = __builtin_amdgcn_mfma_f32_32x32x16_bf16(v2, pf2.v, acc_o[dt], 0, 0, 0);
        acc_o[dt] = __builtin_amdgcn_mfma_f32_32x32x16_bf16(v3, pf3.v, acc_o[dt], 0, 0, 0);
      }
    }
    __builtin_amdgcn_s_setprio(0);
    __syncthreads();
    cur ^= 1;
  }

  const float inv = 1.f / lrun;
  unsigned short* op = AO + qrow * (HQ * DH) + h * DH;
#pragma unroll
  for (int dt = 0; dt < 4; ++dt) {
#pragma unroll
    for (int g2 = 0; g2 < 4; ++g2) {
      u16x4 w;
#pragma unroll
      for (int jj = 0; jj < 4; ++jj) w[jj] = f2bf(acc_o[dt][g2 * 4 + jj] * inv);
      *reinterpret_cast<u16x4*>(op + dt * 32 + g2 * 8 + 4 * hi) = w;
    }
  }
}

// ---------------- launch ----------------------------------------------------
extern "C" void kernel_launch(void* const* d_in, const int* in_sizes, int n_in,
                              void* d_out, int out_size, void* d_ws, size_t ws_size,
                              hipStream_t stream) {
  const float* x  = (const float*)d_in[0];
  const float* wq = (const float*)d_in[1];
  const float* wk = (const float*)d_in[2];
  const float* wv = (const float*)d_in[3];
  const float* wo = (const float*)d_in[4];
  float* out = (float*)d_out;

  const size_t N_X  = (size_t)BATCH * SEQT * DMODEL;
  const size_t N_WQ = (size_t)HQ * DH * DMODEL;
  const size_t N_WK = (size_t)HKV * DH * DMODEL;
  const size_t N_Q  = (size_t)BATCH * SEQT * HQ * DH;
  const size_t N_K  = (size_t)BATCH * SEQT * HKV * DH;

  unsigned short* xb  = (unsigned short*)d_ws;
  unsigned short* wqb = xb  + N_X;
  unsigned short* wkb = wqb + N_WQ;
  unsigned short* wvb = wkb + N_WK;
  unsigned short* wob = wvb + N_WK;
  unsigned short* Qb  = wob + N_WQ;
  unsigned short* Kb  = Qb  + N_Q;
  unsigned short* VTb = Kb  + N_K;
  unsigned short* AOb = VTb + N_K;

  cast_all_kernel<<<dim3(9216), dim3(256), 0, stream>>>(
      x, wq, wk, wv, wo, xb, wqb, wkb, wvb, wob);

  // Q = x @ wq^T : [4096, 2048]
  gemm_bt<true><<<dim3(32, 16, 1), 256, 0, stream>>>(xb, wqb, Qb, 2048, DMODEL);
  // K-proj + V^T-proj fused (256 blocks)
  gemm_kv<<<dim3(256), 256, 0, stream>>>(xb, wkb, wvb, Kb, VTb);
  // attention
  attn_kernel<<<dim3(512, 1, 1), 256, 0, stream>>>(Qb, Kb, VTb, AOb);
  // out = AO @ wo^T : [4096, 2048] f32
  gemm_bt<false><<<dim3(32, 16, 1), 256, 0, stream>>>(AOb, wob, out, 2048, DMODEL);
}

// Round 4
// 211.080 us; speedup vs baseline: 2.1229x; 1.0170x over previous
//
#include <hip/hip_runtime.h>
#include <hip/hip_bf16.h>
#include <stdint.h>

#define DMODEL 2048
#define HQ 16
#define HKV 4
#define DH 128
#define SEQT 2048
#define BATCH 2

typedef __bf16 bf16x8 __attribute__((ext_vector_type(8)));
typedef float f32x4 __attribute__((ext_vector_type(4)));
typedef float f32x16 __attribute__((ext_vector_type(16)));
typedef unsigned short u16x4 __attribute__((ext_vector_type(4)));
typedef unsigned short u16x8 __attribute__((ext_vector_type(8)));

__device__ __forceinline__ unsigned short f2bf(float x) {
  __hip_bfloat16 h = __float2bfloat16(x);
  return __builtin_bit_cast(unsigned short, h);
}
__device__ __forceinline__ unsigned int pack2(float a, float b) {
  return (unsigned int)f2bf(a) | ((unsigned int)f2bf(b) << 16);
}

__device__ __forceinline__ void gload_lds16(const void* g, void* lds) {
  __builtin_amdgcn_global_load_lds(
      (const __attribute__((address_space(1))) void*)(uintptr_t)g,
      (__attribute__((address_space(3))) void*)(uint32_t)(uintptr_t)lds,
      16, 0, 0);
}

// ---------------- fused cast f32 -> bf16 (all 5 tensors; wq pre-scaled) -----
__global__ __launch_bounds__(256) void cast_all_kernel(
    const float* __restrict__ x, const float* __restrict__ wq,
    const float* __restrict__ wk, const float* __restrict__ wv,
    const float* __restrict__ wo,
    unsigned short* __restrict__ xb, unsigned short* __restrict__ wqb,
    unsigned short* __restrict__ wkb, unsigned short* __restrict__ wvb,
    unsigned short* __restrict__ wob) {
  int i = blockIdx.x * 256 + threadIdx.x;
  const float* in; unsigned short* out; int off; float s = 1.0f;
  if (i < 1048576)      { in = x;  out = xb;  off = i; }
  else if (i < 1572864) { in = wq; out = wqb; off = i - 1048576; s = 0.1275174473f; }
  else if (i < 1703936) { in = wk; out = wkb; off = i - 1572864; }
  else if (i < 1835008) { in = wv; out = wvb; off = i - 1703936; }
  else                  { in = wo; out = wob; off = i - 1835008; }
  const float4* p = reinterpret_cast<const float4*>(in) + (size_t)off * 2;
  float4 a = p[0], b = p[1];
  u16x8 o;
  o[0] = f2bf(a.x * s); o[1] = f2bf(a.y * s); o[2] = f2bf(a.z * s); o[3] = f2bf(a.w * s);
  o[4] = f2bf(b.x * s); o[5] = f2bf(b.y * s); o[6] = f2bf(b.z * s); o[7] = f2bf(b.w * s);
  *(reinterpret_cast<u16x8*>(out) + off) = o;
}

// ---------------- GEMM body: C[m,n]=sum_k A[m,k]*B[n,k], BK=64 (2x32 halves)
template <bool OUT_BF16>
__device__ __forceinline__ void gemm_body(
    unsigned short* As, unsigned short* Bs,
    const unsigned short* __restrict__ A, const unsigned short* __restrict__ B,
    void* __restrict__ Cv, int N, int K, int row0, int col0) {
  const int tid = threadIdx.x;
  const int wave = tid >> 6, lane = tid & 63;
  const int wr = (wave >> 1) * 64, wc = (wave & 1) * 64;
  const int l15 = lane & 15, l4 = lane >> 4;
  const int srow = wave * 32 + (lane >> 2);
  const int scol = (lane & 3) * 8;

  f32x4 acc[4][4] = {};

  for (int k0 = 0; k0 < K; k0 += 64) {
#pragma unroll
    for (int h = 0; h < 2; ++h) {
      const unsigned short* gA = A + (size_t)(row0 + srow) * K + k0 + h * 32 + scol;
      gload_lds16(gA, (char*)As + h * 8192 + wave * 2048);
      gload_lds16(gA + (size_t)16 * K, (char*)As + h * 8192 + wave * 2048 + 1024);
      const unsigned short* gB = B + (size_t)(col0 + srow) * K + k0 + h * 32 + scol;
      gload_lds16(gB, (char*)Bs + h * 8192 + wave * 2048);
      gload_lds16(gB + (size_t)16 * K, (char*)Bs + h * 8192 + wave * 2048 + 1024);
    }
    __syncthreads();

    bf16x8 af[2][4], bfr[2][4];
#pragma unroll
    for (int h = 0; h < 2; ++h)
#pragma unroll
      for (int i = 0; i < 4; ++i) {
        af[h][i]  = *reinterpret_cast<const bf16x8*>(&As[h * 4096 + (wr + i * 16 + l15) * 32 + l4 * 8]);
        bfr[h][i] = *reinterpret_cast<const bf16x8*>(&Bs[h * 4096 + (wc + i * 16 + l15) * 32 + l4 * 8]);
      }
#pragma unroll
    for (int h = 0; h < 2; ++h)
#pragma unroll
      for (int i = 0; i < 4; ++i)
#pragma unroll
        for (int j = 0; j < 4; ++j)
          acc[i][j] = __builtin_amdgcn_mfma_f32_16x16x32_bf16(af[h][i], bfr[h][j], acc[i][j], 0, 0, 0);
    __syncthreads();
  }

#pragma unroll
  for (int i = 0; i < 4; ++i) {
    const int rrow = row0 + wr + i * 16 + l4 * 4;
#pragma unroll
    for (int j = 0; j < 4; ++j) {
      const int ccol = col0 + wc + j * 16 + l15;
#pragma unroll
      for (int r = 0; r < 4; ++r) {
        const size_t idx = (size_t)(rrow + r) * N + ccol;
        if constexpr (OUT_BF16)
          ((unsigned short*)Cv)[idx] = f2bf(acc[i][j][r]);
        else
          ((float*)Cv)[idx] = acc[i][j][r];
      }
    }
  }
}

// Q-proj (0..511) + K-proj (512..639) + V^T-proj (640..767), one launch
__global__ __launch_bounds__(256) void gemm_qkv(
    const unsigned short* __restrict__ xb, const unsigned short* __restrict__ wqb,
    const unsigned short* __restrict__ wkb, const unsigned short* __restrict__ wvb,
    unsigned short* __restrict__ Qb, unsigned short* __restrict__ Kb,
    unsigned short* __restrict__ VTb) {
  __shared__ alignas(16) unsigned short As[2][128 * 32];
  __shared__ alignas(16) unsigned short Bs[2][128 * 32];
  const int bid = blockIdx.x;
  if (bid < 512) {
    gemm_body<true>(&As[0][0], &Bs[0][0], xb, wqb, Qb, 2048, DMODEL,
                    (bid >> 4) * 128, (bid & 15) * 128);
  } else if (bid < 640) {
    const int r = bid - 512;
    gemm_body<true>(&As[0][0], &Bs[0][0], xb, wkb, Kb, 512, DMODEL,
                    (r >> 2) * 128, (r & 3) * 128);
  } else {
    const int r = bid - 640;
    const int tz = r & 1, ty = (r >> 1) & 15, tx = r >> 5;
    gemm_body<true>(&As[0][0], &Bs[0][0], wvb,
                    xb + (size_t)tz * SEQT * DMODEL,
                    VTb + (size_t)tz * 512 * SEQT, SEQT, DMODEL,
                    tx * 128, ty * 128);
  }
}

template <bool OUT_BF16>
__global__ __launch_bounds__(256) void gemm_bt(
    const unsigned short* __restrict__ A, const unsigned short* __restrict__ B,
    void* __restrict__ Cv, int N, int K) {
  __shared__ alignas(16) unsigned short As[2][128 * 32];
  __shared__ alignas(16) unsigned short Bs[2][128 * 32];
  gemm_body<OUT_BF16>(&As[0][0], &Bs[0][0], A, B, Cv, N, K,
                      blockIdx.x * 128, blockIdx.y * 128);
}

// ---------------- attention tile pass (one 64-kv tile vs one 32-q tile) -----
__device__ __forceinline__ void tile_pass(
    const char* ksb, const char* vsb, int lane, int hi, int lq,
    int kvb, int q0, const bf16x8* qf, f32x16* acc, float& mrun, float& lrun) {
  const bool s1v = (kvb + 32 <= q0);
  const bool d0 = (kvb == q0), d1 = (kvb + 32 == q0);

  f32x16 st0 = {}, st1 = {};
  __builtin_amdgcn_s_setprio(1);
#pragma unroll
  for (int dc = 0; dc < 8; ++dc) {
    bf16x8 kf = *reinterpret_cast<const bf16x8*>(ksb + dc * 1024 + lane * 16);
    st0 = __builtin_amdgcn_mfma_f32_32x32x16_bf16(kf, qf[dc], st0, 0, 0, 0);
  }
  if (s1v) {
#pragma unroll
    for (int dc = 0; dc < 8; ++dc) {
      bf16x8 kf = *reinterpret_cast<const bf16x8*>(ksb + (8 + dc) * 1024 + lane * 16);
      st1 = __builtin_amdgcn_mfma_f32_32x32x16_bf16(kf, qf[dc], st1, 0, 0, 0);
    }
  }
  __builtin_amdgcn_s_setprio(0);

  float p0[16], p1[16];
#pragma unroll
  for (int r = 0; r < 16; ++r) p0[r] = st0[r];
  if (d0) {  // wave-uniform: only on diagonal tile
#pragma unroll
    for (int r = 0; r < 16; ++r) {
      const int srw = (r & 3) + 8 * (r >> 2) + 4 * hi;
      if (srw > lq) p0[r] = -INFINITY;
    }
  }
  float tmax = -INFINITY;
#pragma unroll
  for (int r = 0; r < 16; ++r) tmax = fmaxf(tmax, p0[r]);
  if (s1v) {
#pragma unroll
    for (int r = 0; r < 16; ++r) p1[r] = st1[r];
    if (d1) {
#pragma unroll
      for (int r = 0; r < 16; ++r) {
        const int srw = (r & 3) + 8 * (r >> 2) + 4 * hi;
        if (srw > lq) p1[r] = -INFINITY;
      }
    }
#pragma unroll
    for (int r = 0; r < 16; ++r) tmax = fmaxf(tmax, p1[r]);
  }
  tmax = fmaxf(tmax, __shfl_xor(tmax, 32));
  if (!__all(tmax <= mrun)) {
    const float mnew = fmaxf(mrun, tmax);
    const float fsc = __builtin_amdgcn_exp2f(mrun - mnew);
    lrun *= fsc;
#pragma unroll
    for (int dt = 0; dt < 4; ++dt)
#pragma unroll
      for (int r = 0; r < 16; ++r) acc[dt][r] *= fsc;
    mrun = mnew;
  }
  float psum = 0.f;
#pragma unroll
  for (int r = 0; r < 16; ++r) { p0[r] = __builtin_amdgcn_exp2f(p0[r] - mrun); psum += p0[r]; }
  if (s1v) {
#pragma unroll
    for (int r = 0; r < 16; ++r) { p1[r] = __builtin_amdgcn_exp2f(p1[r] - mrun); psum += p1[r]; }
  }
  psum += __shfl_xor(psum, 32);
  lrun += psum;

  union { unsigned int u[4]; bf16x8 v; } pf0, pf1, pf2, pf3;
  {
    unsigned int x0 = pack2(p0[0], p0[1]),  x1 = pack2(p0[2], p0[3]);
    unsigned int x2 = pack2(p0[4], p0[5]),  x3 = pack2(p0[6], p0[7]);
    unsigned int x4 = pack2(p0[8], p0[9]),  x5 = pack2(p0[10], p0[11]);
    unsigned int x6 = pack2(p0[12], p0[13]), x7 = pack2(p0[14], p0[15]);
    unsigned int x0s = __shfl_xor(x0, 32), x1s = __shfl_xor(x1, 32);
    unsigned int x2s = __shfl_xor(x2, 32), x3s = __shfl_xor(x3, 32);
    unsigned int x4s = __shfl_xor(x4, 32), x5s = __shfl_xor(x5, 32);
    unsigned int x6s = __shfl_xor(x6, 32), x7s = __shfl_xor(x7, 32);
    pf0.u[0] = hi ? x2s : x0;  pf0.u[1] = hi ? x3s : x1;
    pf0.u[2] = hi ? x2  : x0s; pf0.u[3] = hi ? x3  : x1s;
    pf1.u[0] = hi ? x6s : x4;  pf1.u[1] = hi ? x7s : x5;
    pf1.u[2] = hi ? x6  : x4s; pf1.u[3] = hi ? x7  : x5s;
  }
  if (s1v) {
    unsigned int x0 = pack2(p1[0], p1[1]),  x1 = pack2(p1[2], p1[3]);
    unsigned int x2 = pack2(p1[4], p1[5]),  x3 = pack2(p1[6], p1[7]);
    unsigned int x4 = pack2(p1[8], p1[9]),  x5 = pack2(p1[10], p1[11]);
    unsigned int x6 = pack2(p1[12], p1[13]), x7 = pack2(p1[14], p1[15]);
    unsigned int x0s = __shfl_xor(x0, 32), x1s = __shfl_xor(x1, 32);
    unsigned int x2s = __shfl_xor(x2, 32), x3s = __shfl_xor(x3, 32);
    unsigned int x4s = __shfl_xor(x4, 32), x5s = __shfl_xor(x5, 32);
    unsigned int x6s = __shfl_xor(x6, 32), x7s = __shfl_xor(x7, 32);
    pf2.u[0] = hi ? x2s : x0;  pf2.u[1] = hi ? x3s : x1;
    pf2.u[2] = hi ? x2  : x0s; pf2.u[3] = hi ? x3  : x1s;
    pf3.u[0] = hi ? x6s : x4;  pf3.u[1] = hi ? x7s : x5;
    pf3.u[2] = hi ? x6  : x4s; pf3.u[3] = hi ? x7  : x5s;
  }

  __builtin_amdgcn_s_setprio(1);
#pragma unroll
  for (int dt = 0; dt < 4; ++dt) {
    bf16x8 v0 = *reinterpret_cast<const bf16x8*>(vsb + (dt * 4 + 0) * 1024 + lane * 16);
    bf16x8 v1 = *reinterpret_cast<const bf16x8*>(vsb + (dt * 4 + 1) * 1024 + lane * 16);
    acc[dt] = __builtin_amdgcn_mfma_f32_32x32x16_bf16(v0, pf0.v, acc[dt], 0, 0, 0);
    acc[dt] = __builtin_amdgcn_mfma_f32_32x32x16_bf16(v1, pf1.v, acc[dt], 0, 0, 0);
  }
  if (s1v) {
#pragma unroll
    for (int dt = 0; dt < 4; ++dt) {
      bf16x8 v2 = *reinterpret_cast<const bf16x8*>(vsb + (dt * 4 + 2) * 1024 + lane * 16);
      bf16x8 v3 = *reinterpret_cast<const bf16x8*>(vsb + (dt * 4 + 3) * 1024 + lane * 16);
      acc[dt] = __builtin_amdgcn_mfma_f32_32x32x16_bf16(v2, pf2.v, acc[dt], 0, 0, 0);
      acc[dt] = __builtin_amdgcn_mfma_f32_32x32x16_bf16(v3, pf3.v, acc[dt], 0, 0, 0);
    }
  }
  __builtin_amdgcn_s_setprio(0);
}

// ---------------- fused causal GQA flash attention ---------------------------
// Block = (b, hk, pair p): 4 waves = 4 q-heads. Each wave processes TWO
// q-tiles (jl = 63-p long, js = p short); short tile's kv range is a prefix
// of the long one -> one kv loop, shared K/V staging, constant per-block work
// (perfect balance). KVBLK=64, double-buffered LDS prefetch.
__global__ __launch_bounds__(256, 1) void attn_kernel(
    const unsigned short* __restrict__ Q, const unsigned short* __restrict__ Kc,
    const unsigned short* __restrict__ VT, unsigned short* __restrict__ AO) {
  __shared__ alignas(16) unsigned short Ks[2][16 * 512];
  __shared__ alignas(16) unsigned short Vs[2][16 * 512];

  const int tid = threadIdx.x;
  const int wave = tid >> 6, lane = tid & 63;
  const int bid = blockIdx.x;
  const int bhk = bid & 7;                   // XCD-pinned
  const int pairidx = bid >> 3;              // 0..31
  const int b = bhk >> 2, hk = bhk & 3;
  const int h = hk + wave * 4;
  const int jl = 63 - pairidx, js = pairidx;
  const int q0l = jl * 32, q0s = js * 32;
  const int jtl = jl >> 1, jts = js >> 1;
  const int lq = lane & 31, hi = lane >> 5;

  const size_t qrowL = (size_t)(b * SEQT + q0l + lq);
  const size_t qrowS = (size_t)(b * SEQT + q0s + lq);
  bf16x8 qfL[8], qfS[8];
  {
    const unsigned short* qpL = Q + qrowL * (HQ * DH) + h * DH + hi * 8;
    const unsigned short* qpS = Q + qrowS * (HQ * DH) + h * DH + hi * 8;
#pragma unroll
    for (int dc = 0; dc < 8; ++dc) {
      qfL[dc] = *reinterpret_cast<const bf16x8*>(qpL + dc * 16);
      qfS[dc] = *reinterpret_cast<const bf16x8*>(qpS + dc * 16);
    }
  }

  f32x16 accL[4] = {}, accS[4] = {};
  float mL = -INFINITY, lL = 0.f, mS = -INFINITY, lS = 0.f;

  const unsigned short* kbase = Kc + (size_t)b * SEQT * (HKV * DH) + hk * DH;
  const unsigned short* vtb = VT + ((size_t)b * (HKV * DH) + hk * DH) * SEQT;

  auto STAGE = [&](int buf, int kvb2) {
#pragma unroll
    for (int i = 0; i < 4; ++i) {
      const int f = i * 4 + wave;
      const int sub = f >> 3, dc = f & 7;
      const unsigned short* g = kbase + (size_t)(kvb2 + sub * 32 + lq) * (HKV * DH) + dc * 16 + hi * 8;
      gload_lds16(g, (char*)Ks[buf] + f * 1024);
    }
#pragma unroll
    for (int i = 0; i < 4; ++i) {
      const int f = i * 4 + wave;
      const int dt = f >> 2, ks = f & 3;
      const unsigned short* g = vtb + (size_t)(dt * 32 + lq) * SEQT + kvb2 + ks * 16 + hi * 8;
      gload_lds16(g, (char*)Vs[buf] + f * 1024);
    }
  };

  STAGE(0, 0);
  __syncthreads();
  int cur = 0;

  for (int t = 0; t <= jtl; ++t) {
    if (t < jtl) STAGE(cur ^ 1, (t + 1) * 64);
    const char* ksb = (const char*)Ks[cur];
    const char* vsb = (const char*)Vs[cur];
    tile_pass(ksb, vsb, lane, hi, lq, t * 64, q0l, qfL, accL, mL, lL);
    if (t <= jts)
      tile_pass(ksb, vsb, lane, hi, lq, t * 64, q0s, qfS, accS, mS, lS);
    __syncthreads();
    cur ^= 1;
  }

  auto writeO = [&](const f32x16* acc, float lrun, size_t qrow) {
    const float inv = 1.f / lrun;
    unsigned short* op = AO + qrow * (HQ * DH) + h * DH;
#pragma unroll
    for (int dt = 0; dt < 4; ++dt) {
#pragma unroll
      for (int g2 = 0; g2 < 4; ++g2) {
        u16x4 w;
#pragma unroll
        for (int jj = 0; jj < 4; ++jj) w[jj] = f2bf(acc[dt][g2 * 4 + jj] * inv);
        *reinterpret_cast<u16x4*>(op + dt * 32 + g2 * 8 + 4 * hi) = w;
      }
    }
  };
  writeO(accL, lL, qrowL);
  writeO(accS, lS, qrowS);
}

// ---------------- launch ----------------------------------------------------
extern "C" void kernel_launch(void* const* d_in, const int* in_sizes, int n_in,
                              void* d_out, int out_size, void* d_ws, size_t ws_size,
                              hipStream_t stream) {
  const float* x  = (const float*)d_in[0];
  const float* wq = (const float*)d_in[1];
  const float* wk = (const float*)d_in[2];
  const float* wv = (const float*)d_in[3];
  const float* wo = (const float*)d_in[4];
  float* out = (float*)d_out;

  const size_t N_X  = (size_t)BATCH * SEQT * DMODEL;
  const size_t N_WQ = (size_t)HQ * DH * DMODEL;
  const size_t N_WK = (size_t)HKV * DH * DMODEL;
  const size_t N_Q  = (size_t)BATCH * SEQT * HQ * DH;
  const size_t N_K  = (size_t)BATCH * SEQT * HKV * DH;

  unsigned short* xb  = (unsigned short*)d_ws;
  unsigned short* wqb = xb  + N_X;
  unsigned short* wkb = wqb + N_WQ;
  unsigned short* wvb = wkb + N_WK;
  unsigned short* wob = wvb + N_WK;
  unsigned short* Qb  = wob + N_WQ;
  unsigned short* Kb  = Qb  + N_Q;
  unsigned short* VTb = Kb  + N_K;
  unsigned short* AOb = VTb + N_K;

  cast_all_kernel<<<dim3(9216), dim3(256), 0, stream>>>(
      x, wq, wk, wv, wo, xb, wqb, wkb, wvb, wob);

  gemm_qkv<<<dim3(768), 256, 0, stream>>>(xb, wqb, wkb, wvb, Qb, Kb, VTb);
  attn_kernel<<<dim3(256, 1, 1), 256, 0, stream>>>(Qb, Kb, VTb, AOb);
  gemm_bt<false><<<dim3(32, 16, 1), 256, 0, stream>>>(AOb, wob, out, 2048, DMODEL);
}